// Round 4
// baseline (456.235 us; speedup 1.0000x reference)
//
#include <hip/hip_runtime.h>
#include <type_traits>

#define Bb 256
#define Tt 512
#define Kk 128
#define LN2F 0.69314718055994531f

typedef _Float16 half4_t __attribute__((ext_vector_type(4)));
typedef _Float16 half2_t __attribute__((ext_vector_type(2)));
typedef float    floatx4 __attribute__((ext_vector_type(4)));

// cvt_pkrtz returns __fp16x2; bit-cast to our half2_t (_Float16x2)
__device__ __forceinline__ half2_t pkrtz(float a, float b) {
    return __builtin_bit_cast(half2_t, __builtin_amdgcn_cvt_pkrtz(a, b));
}

// ---------------- pass 1a: P = exp(logits) in f16 (memory-bound) ----------
__global__ __launch_bounds__(256) void exp_kernel(const float* __restrict__ lg,
                                                  _Float16* __restrict__ P, int n4) {
    int i = blockIdx.x * blockDim.x + threadIdx.x;
    const int stride = gridDim.x * blockDim.x;
    const float4* src = (const float4*)lg;
    half4_t* dst = (half4_t*)P;
    for (; i < n4; i += stride) {
        float4 v = src[i];
        half4_t h;
        h[0] = (_Float16)__expf(v.x);  // RNE cvt (unbiased)
        h[1] = (_Float16)__expf(v.y);
        h[2] = (_Float16)__expf(v.z);
        h[3] = (_Float16)__expf(v.w);
        dst[i] = h;
    }
}

// ---------------- pass 1b: gold-path score (1 block / batch) --------------
__global__ __launch_bounds__(64) void score_kernel(const float* __restrict__ lg,
                                                   const int* __restrict__ labels,
                                                   const int* __restrict__ seq_lens,
                                                   const float* __restrict__ trans,
                                                   float* __restrict__ out) {
    const int b = blockIdx.x, lane = threadIdx.x;
    const int* lab = labels + b * Tt;
    const float* L = lg + (size_t)b * Tt * Kk;
    const int Lb = seq_lens[b];
    float s = 0.f;
    for (int t = lane; t < Tt; t += 64) {
        if (t < Lb) {
            int cur = lab[t];
            s += L[(size_t)t * Kk + cur];
            if (t >= 1) s += trans[lab[t - 1] * Kk + cur];
        }
    }
    #pragma unroll
    for (int o = 32; o > 0; o >>= 1) s += __shfl_down(s, o, 64);
    if (lane == 0) atomicAdd(out, -s);
}

// ---------------- pass 2: forward recursion, 1 wave = 16 batches ----------
// State S[k][b] (128x16, linear space, per-column power-of-2 renorm) lives in
// B-frag registers; E^T = exp(trans)^T constant in A-frag registers.
// v_mfma_f32_16x16x16_f16: D slot (q,r) -> m=4q+r; B slot (q,j) -> k=4q+j;
// m/n maps = lane&15 (m89/m91/m120-verified pattern) => D chains into next B.
template <bool USEP>
__global__ __launch_bounds__(64, 1) void crf_fwd(const _Float16* __restrict__ P,
                                                 const float* __restrict__ lg,
                                                 const float* __restrict__ trans,
                                                 const int* __restrict__ seq_lens,
                                                 float* __restrict__ out) {
    using PB = std::conditional_t<USEP, half4_t, float4>;
    const int lane = threadIdx.x;
    const int q = lane >> 4, c = lane & 15;
    const int b0 = blockIdx.x * 16;
    const int Lc = seq_lens[b0 + c];          // per-column seq len
    int Lmax = Lc;
    Lmax = max(Lmax, __shfl_xor(Lmax, 1, 64));
    Lmax = max(Lmax, __shfl_xor(Lmax, 2, 64));
    Lmax = max(Lmax, __shfl_xor(Lmax, 4, 64));
    Lmax = max(Lmax, __shfl_xor(Lmax, 8, 64));

    // E fragments: A slot (q,c,reg j) = Ehat^T[m=16mt+c][k=16kc+4q+j]
    half4_t E[8][8];
    #pragma unroll
    for (int mt = 0; mt < 8; ++mt)
        #pragma unroll
        for (int kc = 0; kc < 8; ++kc) {
            half4_t e;
            #pragma unroll
            for (int j = 0; j < 4; ++j)
                e[j] = (_Float16)__expf(trans[(16 * kc + 4 * q + j) * Kk + 16 * mt + c]);
            E[mt][kc] = e;
        }

    const _Float16* Pb = USEP ? (P + (size_t)(b0 + c) * Tt * Kk) : nullptr;
    const float*    Gb = lg + (size_t)(b0 + c) * Tt * Kk;

    auto loadfrag = [&](int tt, int mt) -> PB {
        if constexpr (USEP)
            return *(const PB*)(Pb + (size_t)tt * Kk + 16 * mt + 4 * q);
        else
            return *(const PB*)(Gb + (size_t)tt * Kk + 16 * mt + 4 * q);
    };
    auto toh = [&](const PB& v, half2_t& lo, half2_t& hi) {
        if constexpr (USEP) {
            lo = (half2_t){v[0], v[1]};
            hi = (half2_t){v[2], v[3]};
        } else {
            lo = pkrtz(__expf(v.x), __expf(v.y));
            hi = pkrtz(__expf(v.z), __expf(v.w));
        }
    };

    half4_t S[8];
    int Csum = 0;

    auto freeze = [&](int T) {
        if (__any(T == Lc - 1)) {
            half2_t a2 = (half2_t){(_Float16)0.f, (_Float16)0.f};
            #pragma unroll
            for (int mt = 0; mt < 8; ++mt) {
                a2 += (half2_t){S[mt][0], S[mt][1]};
                a2 += (half2_t){S[mt][2], S[mt][3]};
            }
            float cs = (float)a2[0] + (float)a2[1];
            cs += __shfl_xor(cs, 16, 64);
            cs += __shfl_xor(cs, 32, 64);
            if (T == Lc - 1 && q == 0)
                atomicAdd(out, __logf(cs) + (float)Csum * LN2F);
        }
    };

    // ---- t = 0: S = P(0) ----
    {
        PB b0v[8];
        #pragma unroll
        for (int mt = 0; mt < 8; ++mt) b0v[mt] = loadfrag(0, mt);
        #pragma unroll
        for (int kc = 0; kc < 8; ++kc) {
            half2_t lo, hi;
            toh(b0v[kc], lo, hi);
            S[kc] = (half4_t){lo[0], lo[1], hi[0], hi[1]};
        }
    }
    freeze(0);

    PB bufA[8], bufB[8];
    #pragma unroll
    for (int mt = 0; mt < 8; ++mt) bufA[mt] = loadfrag(1 < Tt ? 1 : Tt - 1, mt);
    #pragma unroll
    for (int mt = 0; mt < 8; ++mt) bufB[mt] = loadfrag(2 < Tt ? 2 : Tt - 1, mt);

    auto step = [&](int T, PB (&buf)[8], int TN) {
        floatx4 D[8];
        #pragma unroll
        for (int mt = 0; mt < 8; ++mt) D[mt] = (floatx4){0.f, 0.f, 0.f, 0.f};
        #pragma unroll
        for (int kc = 0; kc < 8; ++kc)
            #pragma unroll
            for (int mt = 0; mt < 8; ++mt)
                D[mt] = __builtin_amdgcn_mfma_f32_16x16x16f16(E[mt][kc], S[kc], D[mt], 0, 0, 0);
        // per-column exact power-of-2 renorm; sample states 0..15 (spread <= e)
        float ref = fmaxf(fmaxf(D[0][0], D[0][1]), fmaxf(D[0][2], D[0][3]));
        ref = fmaxf(ref, __shfl_xor(ref, 16, 64));
        ref = fmaxf(ref, __shfl_xor(ref, 32, 64));
        int eb = (__builtin_bit_cast(int, ref) >> 23) & 0xff;
        eb = eb < 1 ? 1 : eb;
        const float sc = __builtin_bit_cast(float, (246 - eb) << 23);  // 2^(119-eb)
        Csum += eb - 119;
        const int tclamp = TN > Tt - 1 ? Tt - 1 : TN;
        #pragma unroll
        for (int mt = 0; mt < 8; ++mt) {
            half2_t lo = pkrtz(D[mt][0] * sc, D[mt][1] * sc);
            half2_t hi = pkrtz(D[mt][2] * sc, D[mt][3] * sc);
            half2_t plo, phi;
            toh(buf[mt], plo, phi);
            lo *= plo;                        // v_pk_mul_f16
            hi *= phi;
            S[mt] = (half4_t){lo[0], lo[1], hi[0], hi[1]};
            buf[mt] = loadfrag(tclamp, mt);   // prefetch t+2 (after consume)
        }
        freeze(T);
    };

    int t = 1;
    for (; t + 1 < Lmax; t += 2) {
        step(t, bufA, t + 2);
        step(t + 1, bufB, t + 3);
    }
    if (t < Lmax) step(t, bufA, t + 2);
}

extern "C" void kernel_launch(void* const* d_in, const int* in_sizes, int n_in,
                              void* d_out, int out_size, void* d_ws, size_t ws_size,
                              hipStream_t stream) {
    const float* logits   = (const float*)d_in[0];
    const int*   labels   = (const int*)d_in[1];
    const int*   seq_lens = (const int*)d_in[2];
    const float* trans    = (const float*)d_in[3];
    float* out = (float*)d_out;

    hipMemsetAsync(out, 0, sizeof(float), stream);
    score_kernel<<<dim3(Bb), dim3(64), 0, stream>>>(logits, labels, seq_lens, trans, out);

    const size_t needP = (size_t)Bb * Tt * Kk * sizeof(_Float16);
    if (ws_size >= needP) {
        _Float16* P = (_Float16*)d_ws;
        exp_kernel<<<dim3(1024), dim3(256), 0, stream>>>(logits, P, Bb * Tt * Kk / 4);
        crf_fwd<true><<<dim3(Bb / 16), dim3(64), 0, stream>>>(P, logits, trans, seq_lens, out);
    } else {
        crf_fwd<false><<<dim3(Bb / 16), dim3(64), 0, stream>>>(nullptr, logits, trans, seq_lens, out);
    }
}